// Round 1
// baseline (9796.559 us; speedup 1.0000x reference)
//
#include <hip/hip_runtime.h>
#include <math.h>

#define D 128
#define N_NODES 5000
#define WINDOW 10
#define N_TOTAL 50000
#define NE_INT 131072
#define NE_TMP 90000
#define HID 1024
#define MROWS 16
#define GRU_R 8
#define GBM 64
#define GBN 64
#define GBK 16

// ---------------- init h: h[j] = embed[nodes[j / WINDOW]] ----------------
__global__ void k_init_h(const int* __restrict__ nodes, const float* __restrict__ embed,
                         float* __restrict__ h) {
    int i = blockIdx.x * blockDim.x + threadIdx.x;
    if (i >= N_TOTAL * D) return;
    int row = i >> 7;
    int c = i & 127;
    int n = nodes[row / WINDOW];
    h[i] = embed[n * D + c];
}

// ---------------- edge index builders ----------------
__global__ void k_build_int_edges(const int* __restrict__ ie, int* __restrict__ src,
                                  int* __restrict__ dst) {
    int e = blockIdx.x * blockDim.x + threadIdx.x;
    if (e >= NE_INT) return;
    int t = ie[e * 3 + 0], a = ie[e * 3 + 1], b = ie[e * 3 + 2];
    src[e] = t * N_NODES + a;   // node_idx  (first half of m_in)
    dst[e] = t * N_NODES + b;   // neigh_idx (second half of m_in, aggregation key)
}

__global__ void k_build_tmp_edges(int* __restrict__ src, int* __restrict__ dst) {
    int e = blockIdx.x * blockDim.x + threadIdx.x;
    if (e >= NE_TMP) return;
    int s, d;
    if (e < N_TOTAL - N_NODES) { s = e; d = e + N_NODES; }          // fwd
    else { int q = e - (N_TOTAL - N_NODES); s = q + N_NODES; d = q; } // bwd
    src[e] = s;
    dst[e] = d;
}

// ---------------- fused message MLP + scatter ----------------
// m = relu(relu([h[src]|h[dst]] @ W1 + b1) @ W2 + b2); atomic add into agg[dst], cnt[dst].
__global__ void __launch_bounds__(256) k_msg(
    const float* __restrict__ h, const int* __restrict__ src, const int* __restrict__ dst,
    int nE, const float* __restrict__ W1, const float* __restrict__ b1,
    const float* __restrict__ W2, const float* __restrict__ b2,
    float* __restrict__ agg, float* __restrict__ cnt)
{
    __shared__ float Ain[MROWS][2 * D];  // 16 x 256 input tile
    __shared__ float Hid[MROWS][64];     // hidden chunk
    __shared__ int sD[MROWS];

    int t = threadIdx.x;
    int e0 = blockIdx.x * MROWS;

    // gather input tile: row r = [h[src[e]] | h[dst[e]]]
    for (int r = 0; r < MROWS; ++r) {
        int e = e0 + r;
        int s = 0, d = 0;
        if (e < nE) { s = src[e]; d = dst[e]; }
        float v = (t < D) ? h[s * D + t] : h[d * D + (t - D)];
        Ain[r][t] = v;
        if (t == 0) sD[r] = d;
    }
    __syncthreads();

    // GEMM2 accumulators: thread owns col2 = t&127, rows rowg*8..+7
    int col2 = t & (D - 1);
    int rowg = t >> 7;
    float macc[8];
#pragma unroll
    for (int i = 0; i < 8; ++i) macc[i] = 0.f;

    int colh = t & 63;
    int rg = t >> 6;  // 0..3 -> rows rg*4..+3

    for (int hc = 0; hc < HID / 64; ++hc) {
        // GEMM1: Hid[16][64] = relu(Ain @ W1[:, hc*64 .. +63] + b1)
        float acc[4];
        float bias1 = b1[hc * 64 + colh];
#pragma unroll
        for (int i = 0; i < 4; ++i) acc[i] = bias1;
        const float* w1p = W1 + hc * 64 + colh;
#pragma unroll 4
        for (int k = 0; k < 2 * D; ++k) {
            float w = w1p[(size_t)k * HID];
#pragma unroll
            for (int i = 0; i < 4; ++i) acc[i] += Ain[rg * 4 + i][k] * w;
        }
        __syncthreads();  // previous chunk's Hid readers done
#pragma unroll
        for (int i = 0; i < 4; ++i) Hid[rg * 4 + i][colh] = fmaxf(acc[i], 0.f);
        __syncthreads();
        // GEMM2 accumulate: macc += Hid @ W2[hc*64 .. +63, :]
        const float* w2p = W2 + (size_t)(hc * 64) * D + col2;
#pragma unroll 8
        for (int k = 0; k < 64; ++k) {
            float w = w2p[(size_t)k * D];
#pragma unroll
            for (int i = 0; i < 8; ++i) macc[i] += Hid[rowg * 8 + i][k] * w;
        }
    }

    // epilogue: relu(+b2), scatter with atomics
    float bb = b2[col2];
#pragma unroll
    for (int i = 0; i < 8; ++i) {
        int r = rowg * 8 + i;
        int e = e0 + r;
        if (e < nE) {
            float m = fmaxf(macc[i] + bb, 0.f);
            atomicAdd(&agg[(size_t)sD[r] * D + col2], m);
        }
    }
    if (t < MROWS) {
        int e = e0 + t;
        if (e < nE) atomicAdd(&cnt[sD[t]], 1.0f);
    }
}

// ---------------- fused seg-mean-div + GRU (in place on h) ----------------
__global__ void __launch_bounds__(128) k_gru(
    const float* __restrict__ agg, const float* __restrict__ cnt, float* __restrict__ h,
    const float* __restrict__ W, const float* __restrict__ U, const float* __restrict__ b)
{
    __shared__ float ax[GRU_R][D];
    __shared__ float hx[GRU_R][D];
    __shared__ float xg[GRU_R][3 * D];
    __shared__ float hg[GRU_R][3 * D];

    int t = threadIdx.x;  // 0..127
    int r0 = blockIdx.x * GRU_R;

    for (int r = 0; r < GRU_R; ++r) {
        int row = r0 + r;
        float c = cnt[row];
        float a = agg[(size_t)row * D + t];
        ax[r][t] = (c > 0.f) ? a / c : 0.f;
        hx[r][t] = h[(size_t)row * D + t];
    }
    __syncthreads();

#pragma unroll
    for (int p = 0; p < 3; ++p) {
        int c = t + p * D;
        float accx[GRU_R], acch[GRU_R];
        float bx_ = b[c], bh_ = b[3 * D + c];
#pragma unroll
        for (int r = 0; r < GRU_R; ++r) { accx[r] = bx_; acch[r] = bh_; }
        for (int k = 0; k < D; ++k) {
            float w = W[(size_t)k * 3 * D + c];
            float u = U[(size_t)k * 3 * D + c];
#pragma unroll
            for (int r = 0; r < GRU_R; ++r) {
                accx[r] += ax[r][k] * w;
                acch[r] += hx[r][k] * u;
            }
        }
#pragma unroll
        for (int r = 0; r < GRU_R; ++r) { xg[r][c] = accx[r]; hg[r][c] = acch[r]; }
    }
    __syncthreads();

    for (int r = 0; r < GRU_R; ++r) {
        int row = r0 + r;
        float z = 1.f / (1.f + expf(-(xg[r][t] + hg[r][t])));
        float rr = 1.f / (1.f + expf(-(xg[r][t + D] + hg[r][t + D])));
        float hc = tanhf(xg[r][t + 2 * D] + rr * hg[r][t + 2 * D]);
        float hv = hx[r][t];
        h[(size_t)row * D + t] = z * hv + (1.f - z) * hc;
    }
}

// ---------------- generic tiled GEMM: C = act(A @ B + bias) ----------------
__global__ void __launch_bounds__(256) k_gemm_bias_act(
    const float* __restrict__ A, const float* __restrict__ B,
    const float* __restrict__ bias, float* __restrict__ C,
    int M, int N, int K, int relu)
{
    __shared__ float As[GBK][GBM];
    __shared__ float Bs[GBK][GBN];
    int t = threadIdx.x;
    int tx = t & 15, ty = t >> 4;
    int bx = blockIdx.x, by = blockIdx.y;
    float acc[4][4] = {};
    int arow = t >> 2;        // 0..63
    int acol4 = (t & 3) * 4;  // 0,4,8,12

    for (int k0 = 0; k0 < K; k0 += GBK) {
        {   // A tile 64x16 -> As[k][m], float4 loads
            int m = by * GBM + arow;
            float4 v = make_float4(0.f, 0.f, 0.f, 0.f);
            if (m < M) v = *(const float4*)(A + (size_t)m * K + k0 + acol4);
            As[acol4 + 0][arow] = v.x;
            As[acol4 + 1][arow] = v.y;
            As[acol4 + 2][arow] = v.z;
            As[acol4 + 3][arow] = v.w;
        }
        {   // B tile 16x64
            int kk = t >> 6;  // 0..3
            int n = t & 63;
#pragma unroll
            for (int p = 0; p < 4; ++p)
                Bs[kk + p * 4][n] = B[(size_t)(k0 + kk + p * 4) * N + bx * GBN + n];
        }
        __syncthreads();
#pragma unroll
        for (int k = 0; k < GBK; ++k) {
            float av[4], bv[4];
#pragma unroll
            for (int i = 0; i < 4; ++i) av[i] = As[k][ty * 4 + i];
#pragma unroll
            for (int j = 0; j < 4; ++j) bv[j] = Bs[k][tx * 4 + j];
#pragma unroll
            for (int i = 0; i < 4; ++i)
#pragma unroll
                for (int j = 0; j < 4; ++j) acc[i][j] += av[i] * bv[j];
        }
        __syncthreads();
    }
#pragma unroll
    for (int i = 0; i < 4; ++i) {
        int m = by * GBM + ty * 4 + i;
        if (m >= M) continue;
#pragma unroll
        for (int j = 0; j < 4; ++j) {
            int n = bx * GBN + tx * 4 + j;
            float v = acc[i][j] + bias[n];
            if (relu) v = fmaxf(v, 0.f);
            C[(size_t)m * N + n] = v;
        }
    }
}

// ---------------- final 512x10 logits + softmax, one wave per row ----------------
__global__ void __launch_bounds__(64) k_logits_softmax(
    const float* __restrict__ r2, const float* __restrict__ W3,
    const float* __restrict__ b3, float* __restrict__ out)
{
    int row = blockIdx.x;
    int t = threadIdx.x;
    float p[10];
#pragma unroll
    for (int j = 0; j < 10; ++j) p[j] = 0.f;
    for (int k = t; k < 512; k += 64) {
        float v = r2[(size_t)row * 512 + k];
#pragma unroll
        for (int j = 0; j < 10; ++j) p[j] += v * W3[k * 10 + j];
    }
#pragma unroll
    for (int j = 0; j < 10; ++j) {
        float s = p[j];
        for (int off = 32; off > 0; off >>= 1) s += __shfl_down(s, off);
        p[j] = s;
    }
    if (t == 0) {
        float mx = -1e30f;
#pragma unroll
        for (int j = 0; j < 10; ++j) { p[j] += b3[j]; mx = fmaxf(mx, p[j]); }
        float sum = 0.f;
#pragma unroll
        for (int j = 0; j < 10; ++j) { p[j] = expf(p[j] - mx); sum += p[j]; }
        float inv = 1.f / sum;
#pragma unroll
        for (int j = 0; j < 10; ++j) out[(size_t)row * 10 + j] = p[j] * inv;
    }
}

extern "C" void kernel_launch(void* const* d_in, const int* in_sizes, int n_in,
                              void* d_out, int out_size, void* d_ws, size_t ws_size,
                              hipStream_t stream)
{
    const int*   ie    = (const int*)d_in[0];
    const int*   nodes = (const int*)d_in[1];
    const float* embed = (const float*)d_in[2];
    const float* mW1   = (const float*)d_in[3];
    const float* mb1   = (const float*)d_in[4];
    const float* mW2   = (const float*)d_in[5];
    const float* mb2   = (const float*)d_in[6];
    const float* giW   = (const float*)d_in[7];
    const float* giU   = (const float*)d_in[8];
    const float* gib   = (const float*)d_in[9];
    const float* gtW   = (const float*)d_in[10];
    const float* gtU   = (const float*)d_in[11];
    const float* gtb   = (const float*)d_in[12];
    const float* rW1   = (const float*)d_in[13];
    const float* rb1   = (const float*)d_in[14];
    const float* rW2   = (const float*)d_in[15];
    const float* rb2   = (const float*)d_in[16];
    const float* rW3   = (const float*)d_in[17];
    const float* rb3   = (const float*)d_in[18];
    float* out = (float*)d_out;

    char* ws = (char*)d_ws;
    size_t off = 0;
    auto alloc = [&](size_t bytes) {
        void* p = ws + off;
        off += (bytes + 255) & ~(size_t)255;
        return p;
    };
    float* h    = (float*)alloc((size_t)N_TOTAL * D * 4);
    float* agg  = (float*)alloc((size_t)N_TOTAL * D * 4);  // reused as r1 in readout
    float* cnt  = (float*)alloc((size_t)N_TOTAL * 4);
    int*   srcA = (int*)alloc((size_t)NE_INT * 4);
    int*   dstA = (int*)alloc((size_t)NE_INT * 4);
    int*   srcT = (int*)alloc((size_t)NE_TMP * 4);
    int*   dstT = (int*)alloc((size_t)NE_TMP * 4);
    float* r2   = (float*)alloc((size_t)N_NODES * 512 * 4);
    float* r1   = agg;  // 5000x1024 fits in agg's 50000x128 region; agg dead after last GRU

    k_init_h<<<(N_TOTAL * D + 255) / 256, 256, 0, stream>>>(nodes, embed, h);
    k_build_int_edges<<<(NE_INT + 255) / 256, 256, 0, stream>>>(ie, srcA, dstA);
    k_build_tmp_edges<<<(NE_TMP + 255) / 256, 256, 0, stream>>>(srcT, dstT);

    for (int it = 0; it < 2; ++it) {
        hipMemsetAsync(agg, 0, (size_t)N_TOTAL * D * 4, stream);
        hipMemsetAsync(cnt, 0, (size_t)N_TOTAL * 4, stream);
        k_msg<<<(NE_INT + MROWS - 1) / MROWS, 256, 0, stream>>>(
            h, srcA, dstA, NE_INT, mW1, mb1, mW2, mb2, agg, cnt);
        k_gru<<<N_TOTAL / GRU_R, 128, 0, stream>>>(agg, cnt, h, giW, giU, gib);

        hipMemsetAsync(agg, 0, (size_t)N_TOTAL * D * 4, stream);
        hipMemsetAsync(cnt, 0, (size_t)N_TOTAL * 4, stream);
        k_msg<<<(NE_TMP + MROWS - 1) / MROWS, 256, 0, stream>>>(
            h, srcT, dstT, NE_TMP, mW1, mb1, mW2, mb2, agg, cnt);
        k_gru<<<N_TOTAL / GRU_R, 128, 0, stream>>>(agg, cnt, h, gtW, gtU, gtb);
    }

    // readout: h[:5000] -> r1 -> r2 -> softmax(out)
    dim3 g1(HID / GBN, (N_NODES + GBM - 1) / GBM);
    k_gemm_bias_act<<<g1, 256, 0, stream>>>(h, rW1, rb1, r1, N_NODES, HID, D, 1);
    dim3 g2(512 / GBN, (N_NODES + GBM - 1) / GBM);
    k_gemm_bias_act<<<g2, 256, 0, stream>>>(r1, rW2, rb2, r2, N_NODES, 512, HID, 1);
    k_logits_softmax<<<N_NODES, 64, 0, stream>>>(r2, rW3, rb3, out);
}

// Round 2
// 1864.200 us; speedup vs baseline: 5.2551x; 5.2551x over previous
//
#include <hip/hip_runtime.h>
#include <math.h>

#define D 128
#define N_NODES 5000
#define WINDOW 10
#define N_TOTAL 50000
#define NE_INT 131072
#define NE_TMP 90000
#define HID 1024

typedef short bf16x8 __attribute__((ext_vector_type(8)));
typedef float f32x4 __attribute__((ext_vector_type(4)));

#define SA 264   // Ain LDS row stride in shorts (256 + 8 pad)
#define SH 136   // 128 + 8 pad
#define SK 136   // 128 + 8 pad

static __device__ __forceinline__ short f2bf(float f) {
    union { float f; unsigned u; } v; v.f = f;
    unsigned r = v.u + 0x7fffu + ((v.u >> 16) & 1u);   // RNE
    return (short)(r >> 16);
}

// ---------------- weight transpose + cvt: out[n*K+k] = bf16(in[k*N+n]) ----------------
__global__ void k_tcvt(const float* __restrict__ in, short* __restrict__ out, int K, int N) {
    int i = blockIdx.x * blockDim.x + threadIdx.x;
    if (i >= N * K) return;
    int n = i / K, k = i - n * K;
    out[i] = f2bf(in[(size_t)k * N + n]);
}

// ---------------- init h: h[j] = embed[nodes[j / WINDOW]] (fp32 + bf16 mirror) ----------------
__global__ void k_init_h(const int* __restrict__ nodes, const float* __restrict__ embed,
                         float* __restrict__ h32, short* __restrict__ h16) {
    int i = blockIdx.x * blockDim.x + threadIdx.x;
    if (i >= N_TOTAL * D) return;
    int row = i >> 7;
    int c = i & 127;
    int n = nodes[row / WINDOW];
    float v = embed[n * D + c];
    h32[i] = v;
    h16[i] = f2bf(v);
}

// ---------------- edge index builders ----------------
__global__ void k_build_int_edges(const int* __restrict__ ie, int* __restrict__ src,
                                  int* __restrict__ dst) {
    int e = blockIdx.x * blockDim.x + threadIdx.x;
    if (e >= NE_INT) return;
    int t = ie[e * 3 + 0], a = ie[e * 3 + 1], b = ie[e * 3 + 2];
    src[e] = t * N_NODES + a;
    dst[e] = t * N_NODES + b;
}

__global__ void k_build_tmp_edges(int* __restrict__ src, int* __restrict__ dst) {
    int e = blockIdx.x * blockDim.x + threadIdx.x;
    if (e >= NE_TMP) return;
    int s, d;
    if (e < N_TOTAL - N_NODES) { s = e; d = e + N_NODES; }
    else { int q = e - (N_TOTAL - N_NODES); s = q + N_NODES; d = q; }
    src[e] = s;
    dst[e] = d;
}

__global__ void k_count(const int* __restrict__ dst, int nE, float* __restrict__ cnt) {
    int e = blockIdx.x * blockDim.x + threadIdx.x;
    if (e >= nE) return;
    atomicAdd(&cnt[dst[e]], 1.0f);
}

// ---------------- fused message MLP (MFMA) + atomic scatter ----------------
// 64 edges/block. hiddenT formulation: GEMM1 computes hidT = W1T @ AinT so C-fragments
// give 4 contiguous channels/lane -> ds_write_b64. GEMM2 computes mT = W2T @ hidT.
__global__ void __launch_bounds__(256, 2) k_msg_mfma(
    const short* __restrict__ h16, const int* __restrict__ src, const int* __restrict__ dst,
    int nE, const short* __restrict__ W1T, const float* __restrict__ b1,
    const short* __restrict__ W2T, const float* __restrict__ b2,
    float* __restrict__ agg)
{
    __shared__ short Ain[64 * SA];   // [edge][0:256) = [h[src] | h[dst]] bf16
    __shared__ short Hid[64 * SH];   // [edge][128] hidden chunk bf16
    __shared__ int sDst[64];

    int t = threadIdx.x;
    int e0 = blockIdx.x * 64;

    // ---- gather: 4 threads per edge row, 16B granules ----
    {
        int r = t >> 2, q = t & 3;
        int e = e0 + r;
        int ec = (e < nE) ? e : (nE - 1);
        int s = src[ec], d = dst[ec];
        if (q == 0) sDst[r] = d;
        const uint4* ps = (const uint4*)(h16 + (size_t)s * D);
        const uint4* pd = (const uint4*)(h16 + (size_t)d * D);
        uint4* ao = (uint4*)(Ain + r * SA);
#pragma unroll
        for (int i = 0; i < 8; ++i) {
            int g = q * 8 + i;
            ao[g] = (g < 16) ? ps[g] : pd[g - 16];
        }
    }
    __syncthreads();

    int w = t >> 6, lane = t & 63;
    int lm = lane & 15, lk = lane >> 4;

    // persistent GEMM2 accumulators: wave w owns out channels [32w, 32w+32)
    f32x4 c2[2][4];
#pragma unroll
    for (int cs = 0; cs < 2; ++cs) {
        int out0 = w * 32 + cs * 16 + lk * 4;
#pragma unroll
        for (int et = 0; et < 4; ++et)
#pragma unroll
            for (int rg = 0; rg < 4; ++rg) c2[cs][et][rg] = b2[out0 + rg];
    }

    for (int hc = 0; hc < 8; ++hc) {   // hidden chunks of 128
        // GEMM1: hidT chunk: wave w computes ch-tiles {2w,2w+1} x 4 edge-tiles, K=256
        f32x4 c1[2][4];
#pragma unroll
        for (int cs = 0; cs < 2; ++cs) {
            int ch0 = hc * 128 + (2 * w + cs) * 16 + lk * 4;
#pragma unroll
            for (int et = 0; et < 4; ++et)
#pragma unroll
                for (int rg = 0; rg < 4; ++rg) c1[cs][et][rg] = b1[ch0 + rg];
        }
#pragma unroll
        for (int kk = 0; kk < 8; ++kk) {
            int ko = kk * 32 + lk * 8;
            bf16x8 a0 = *(const bf16x8*)(W1T + (size_t)(hc * 128 + (2 * w) * 16 + lm) * 256 + ko);
            bf16x8 a1 = *(const bf16x8*)(W1T + (size_t)(hc * 128 + (2 * w + 1) * 16 + lm) * 256 + ko);
            bf16x8 bf[4];
#pragma unroll
            for (int et = 0; et < 4; ++et)
                bf[et] = *(const bf16x8*)(Ain + (et * 16 + lm) * SA + ko);
#pragma unroll
            for (int et = 0; et < 4; ++et) {
                c1[0][et] = __builtin_amdgcn_mfma_f32_16x16x32_bf16(a0, bf[et], c1[0][et], 0, 0, 0);
                c1[1][et] = __builtin_amdgcn_mfma_f32_16x16x32_bf16(a1, bf[et], c1[1][et], 0, 0, 0);
            }
        }
        __syncthreads();   // previous chunk's GEMM2 Hid-readers done
        // relu + cvt + write Hid[edge][ch_in] (4 contiguous ch -> 8B store)
#pragma unroll
        for (int cs = 0; cs < 2; ++cs) {
            int ch_in = (2 * w + cs) * 16 + lk * 4;
#pragma unroll
            for (int et = 0; et < 4; ++et) {
                int edge = et * 16 + lm;
                short4 sv;
                sv.x = f2bf(fmaxf(c1[cs][et][0], 0.f));
                sv.y = f2bf(fmaxf(c1[cs][et][1], 0.f));
                sv.z = f2bf(fmaxf(c1[cs][et][2], 0.f));
                sv.w = f2bf(fmaxf(c1[cs][et][3], 0.f));
                *(short4*)(Hid + edge * SH + ch_in) = sv;
            }
        }
        __syncthreads();
        // GEMM2 accumulate: K-chunk 128
#pragma unroll
        for (int kk = 0; kk < 4; ++kk) {
            int ko = kk * 32 + lk * 8;
            bf16x8 a0 = *(const bf16x8*)(W2T + (size_t)(w * 32 + lm) * 1024 + hc * 128 + ko);
            bf16x8 a1 = *(const bf16x8*)(W2T + (size_t)(w * 32 + 16 + lm) * 1024 + hc * 128 + ko);
            bf16x8 bf[4];
#pragma unroll
            for (int et = 0; et < 4; ++et)
                bf[et] = *(const bf16x8*)(Hid + (et * 16 + lm) * SH + ko);
#pragma unroll
            for (int et = 0; et < 4; ++et) {
                c2[0][et] = __builtin_amdgcn_mfma_f32_16x16x32_bf16(a0, bf[et], c2[0][et], 0, 0, 0);
                c2[1][et] = __builtin_amdgcn_mfma_f32_16x16x32_bf16(a1, bf[et], c2[1][et], 0, 0, 0);
            }
        }
    }

    // ---- scatter: relu + atomicAdd into agg[dst] ----
#pragma unroll
    for (int et = 0; et < 4; ++et) {
        int edge = et * 16 + lm;
        if (e0 + edge >= nE) continue;
        float* ap = agg + (size_t)sDst[edge] * D;
#pragma unroll
        for (int cs = 0; cs < 2; ++cs) {
            int out0 = w * 32 + cs * 16 + lk * 4;
#pragma unroll
            for (int rg = 0; rg < 4; ++rg)
                atomicAdd(ap + out0 + rg, fmaxf(c2[cs][et][rg], 0.f));
        }
    }
}

// ---------------- fused seg-mean + GRU (MFMA), in place on h32/h16 ----------------
__global__ void __launch_bounds__(256, 2) k_gru_mfma(
    const float* __restrict__ agg, const float* __restrict__ cnt,
    float* __restrict__ h32, short* __restrict__ h16,
    const short* __restrict__ WT, const short* __restrict__ UT,
    const float* __restrict__ b)
{
    __shared__ short Ax[64 * SK];   // ax = seg-mean, bf16
    __shared__ short Hx[64 * SK];   // h,   bf16
    int t = threadIdx.x;
    int r0 = blockIdx.x * 64;

    {
        int r = t >> 2, q = t & 3;
        int row = r0 + r;
        int rc = (row < N_TOTAL) ? row : (N_TOTAL - 1);
        float c = cnt[rc];
        float inv = (c > 0.f) ? 1.f / c : 0.f;
        const float4* ag = (const float4*)(agg + (size_t)rc * D);
        const uint4* hp = (const uint4*)(h16 + (size_t)rc * D);
        uint4* hxo = (uint4*)(Hx + r * SK);
#pragma unroll
        for (int i = 0; i < 4; ++i) hxo[q * 4 + i] = hp[q * 4 + i];
#pragma unroll
        for (int i = 0; i < 8; ++i) {
            float4 v = ag[q * 8 + i];
            short4 sv;
            sv.x = f2bf(v.x * inv); sv.y = f2bf(v.y * inv);
            sv.z = f2bf(v.z * inv); sv.w = f2bf(v.w * inv);
            *(short4*)(Ax + r * SK + q * 32 + i * 4) = sv;
        }
    }
    __syncthreads();

    int w = t >> 6, lane = t & 63;
    int lm = lane & 15, lk = lane >> 4;

    for (int g = 0; g < 8; ++g) {   // 16 gate-channels per group
        int ch = g * 16 + lm;
        f32x4 cxz, cxr, cxh, chz, chr_, chh;
#pragma unroll
        for (int rg = 0; rg < 4; ++rg) {
            cxz[rg] = b[ch];        chz[rg] = b[384 + ch];
            cxr[rg] = b[128 + ch];  chr_[rg] = b[384 + 128 + ch];
            cxh[rg] = b[256 + ch];  chh[rg] = b[384 + 256 + ch];
        }
#pragma unroll
        for (int kk = 0; kk < 4; ++kk) {
            int ko = kk * 32 + lk * 8;
            bf16x8 ax = *(const bf16x8*)(Ax + (w * 16 + lm) * SK + ko);
            bf16x8 hx = *(const bf16x8*)(Hx + (w * 16 + lm) * SK + ko);
            bf16x8 bz = *(const bf16x8*)(WT + (size_t)(ch) * 128 + ko);
            bf16x8 br = *(const bf16x8*)(WT + (size_t)(128 + ch) * 128 + ko);
            bf16x8 bh = *(const bf16x8*)(WT + (size_t)(256 + ch) * 128 + ko);
            bf16x8 uz = *(const bf16x8*)(UT + (size_t)(ch) * 128 + ko);
            bf16x8 ur = *(const bf16x8*)(UT + (size_t)(128 + ch) * 128 + ko);
            bf16x8 uh = *(const bf16x8*)(UT + (size_t)(256 + ch) * 128 + ko);
            cxz = __builtin_amdgcn_mfma_f32_16x16x32_bf16(ax, bz, cxz, 0, 0, 0);
            cxr = __builtin_amdgcn_mfma_f32_16x16x32_bf16(ax, br, cxr, 0, 0, 0);
            cxh = __builtin_amdgcn_mfma_f32_16x16x32_bf16(ax, bh, cxh, 0, 0, 0);
            chz = __builtin_amdgcn_mfma_f32_16x16x32_bf16(hx, uz, chz, 0, 0, 0);
            chr_ = __builtin_amdgcn_mfma_f32_16x16x32_bf16(hx, ur, chr_, 0, 0, 0);
            chh = __builtin_amdgcn_mfma_f32_16x16x32_bf16(hx, uh, chh, 0, 0, 0);
        }
#pragma unroll
        for (int rg = 0; rg < 4; ++rg) {
            int row = r0 + w * 16 + lk * 4 + rg;
            if (row >= N_TOTAL) continue;
            float z = 1.f / (1.f + expf(-(cxz[rg] + chz[rg])));
            float r_ = 1.f / (1.f + expf(-(cxr[rg] + chr_[rg])));
            float hcv = tanhf(cxh[rg] + r_ * chh[rg]);
            size_t idx = (size_t)row * D + ch;
            float hold = h32[idx];
            float hnew = z * hold + (1.f - z) * hcv;
            h32[idx] = hnew;
            h16[idx] = f2bf(hnew);
        }
    }
}

// ---------------- generic MFMA GEMM: C = relu(A16 @ B + bias), writes fp32 + bf16 ----------------
// A16: [M][K] bf16 row-major; BT: [N][K] bf16 row-major. Block: 64 rows x 128 cols.
__global__ void __launch_bounds__(256, 2) k_ro_mfma(
    const short* __restrict__ A16, const short* __restrict__ BT,
    const float* __restrict__ bias, float* __restrict__ C32, short* __restrict__ C16,
    int M, int N, int K)
{
    __shared__ short As[64 * SK];
    int t = threadIdx.x;
    int mb = blockIdx.y * 64;
    int nb = blockIdx.x * 128;
    int w = t >> 6, lane = t & 63;
    int lm = lane & 15, lk = lane >> 4;

    f32x4 acc[8];
#pragma unroll
    for (int nt = 0; nt < 8; ++nt) {
        float bv = bias[nb + nt * 16 + lm];
        acc[nt][0] = bv; acc[nt][1] = bv; acc[nt][2] = bv; acc[nt][3] = bv;
    }

    for (int kc = 0; kc < K; kc += 128) {
        __syncthreads();
        {
            int r = t >> 2, q = t & 3;
            int row = mb + r;
            int rc = (row < M) ? row : (M - 1);
            const uint4* ap = (const uint4*)(A16 + (size_t)rc * K + kc);
            uint4* ao = (uint4*)(As + r * SK);
#pragma unroll
            for (int i = 0; i < 4; ++i) ao[q * 4 + i] = ap[q * 4 + i];
        }
        __syncthreads();
#pragma unroll
        for (int kk = 0; kk < 4; ++kk) {
            int ko = kk * 32 + lk * 8;
            bf16x8 a = *(const bf16x8*)(As + (w * 16 + lm) * SK + ko);
#pragma unroll
            for (int nt = 0; nt < 8; ++nt) {
                bf16x8 bfr = *(const bf16x8*)(BT + (size_t)(nb + nt * 16 + lm) * K + kc + ko);
                acc[nt] = __builtin_amdgcn_mfma_f32_16x16x32_bf16(a, bfr, acc[nt], 0, 0, 0);
            }
        }
    }
#pragma unroll
    for (int nt = 0; nt < 8; ++nt) {
        int col = nb + nt * 16 + lm;
#pragma unroll
        for (int rg = 0; rg < 4; ++rg) {
            int row = mb + w * 16 + lk * 4 + rg;
            if (row >= M) continue;
            float v = fmaxf(acc[nt][rg], 0.f);
            C32[(size_t)row * N + col] = v;
            C16[(size_t)row * N + col] = f2bf(v);
        }
    }
}

// ---------------- final 512x10 logits + softmax ----------------
__global__ void __launch_bounds__(64) k_logits_softmax(
    const float* __restrict__ r2, const float* __restrict__ W3,
    const float* __restrict__ b3, float* __restrict__ out)
{
    int row = blockIdx.x;
    int t = threadIdx.x;
    float p[10];
#pragma unroll
    for (int j = 0; j < 10; ++j) p[j] = 0.f;
    for (int k = t; k < 512; k += 64) {
        float v = r2[(size_t)row * 512 + k];
#pragma unroll
        for (int j = 0; j < 10; ++j) p[j] += v * W3[k * 10 + j];
    }
#pragma unroll
    for (int j = 0; j < 10; ++j) {
        float s = p[j];
        for (int off = 32; off > 0; off >>= 1) s += __shfl_down(s, off);
        p[j] = s;
    }
    if (t == 0) {
        float mx = -1e30f;
#pragma unroll
        for (int j = 0; j < 10; ++j) { p[j] += b3[j]; mx = fmaxf(mx, p[j]); }
        float sum = 0.f;
#pragma unroll
        for (int j = 0; j < 10; ++j) { p[j] = expf(p[j] - mx); sum += p[j]; }
        float inv = 1.f / sum;
#pragma unroll
        for (int j = 0; j < 10; ++j) out[(size_t)row * 10 + j] = p[j] * inv;
    }
}

extern "C" void kernel_launch(void* const* d_in, const int* in_sizes, int n_in,
                              void* d_out, int out_size, void* d_ws, size_t ws_size,
                              hipStream_t stream)
{
    const int*   ie    = (const int*)d_in[0];
    const int*   nodes = (const int*)d_in[1];
    const float* embed = (const float*)d_in[2];
    const float* mW1   = (const float*)d_in[3];
    const float* mb1   = (const float*)d_in[4];
    const float* mW2   = (const float*)d_in[5];
    const float* mb2   = (const float*)d_in[6];
    const float* giW   = (const float*)d_in[7];
    const float* giU   = (const float*)d_in[8];
    const float* gib   = (const float*)d_in[9];
    const float* gtW   = (const float*)d_in[10];
    const float* gtU   = (const float*)d_in[11];
    const float* gtb   = (const float*)d_in[12];
    const float* rW1   = (const float*)d_in[13];
    const float* rb1   = (const float*)d_in[14];
    const float* rW2   = (const float*)d_in[15];
    const float* rb2   = (const float*)d_in[16];
    const float* rW3   = (const float*)d_in[17];
    const float* rb3   = (const float*)d_in[18];
    float* out = (float*)d_out;

    char* ws = (char*)d_ws;
    size_t off = 0;
    auto alloc = [&](size_t bytes) {
        void* p = ws + off;
        off += (bytes + 255) & ~(size_t)255;
        return p;
    };
    float* h32   = (float*)alloc((size_t)N_TOTAL * D * 4);
    short* h16   = (short*)alloc((size_t)N_TOTAL * D * 2);
    float* agg   = (float*)alloc((size_t)N_TOTAL * D * 4);   // reused as r1_32 dump
    float* cntA  = (float*)alloc((size_t)N_TOTAL * 4);
    float* cntT  = (float*)alloc((size_t)N_TOTAL * 4);
    int*   srcA  = (int*)alloc((size_t)NE_INT * 4);
    int*   dstA  = (int*)alloc((size_t)NE_INT * 4);
    int*   srcT  = (int*)alloc((size_t)NE_TMP * 4);
    int*   dstT  = (int*)alloc((size_t)NE_TMP * 4);
    short* mW1T  = (short*)alloc((size_t)HID * 256 * 2);
    short* mW2T  = (short*)alloc((size_t)D * HID * 2);
    short* giWT  = (short*)alloc((size_t)384 * D * 2);
    short* giUT  = (short*)alloc((size_t)384 * D * 2);
    short* gtWT  = (short*)alloc((size_t)384 * D * 2);
    short* gtUT  = (short*)alloc((size_t)384 * D * 2);
    short* rW1T  = (short*)alloc((size_t)HID * D * 2);
    short* rW2T  = (short*)alloc((size_t)512 * HID * 2);
    short* r1_16 = (short*)alloc((size_t)N_NODES * HID * 2);
    float* r2_32 = (float*)alloc((size_t)N_NODES * 512 * 4);
    short* r2_16 = (short*)alloc((size_t)N_NODES * 512 * 2); // dump
    float* r1_32 = agg;  // agg dead after last GRU

    // weight repack (bf16, transposed)
    auto tc = [&](const float* in, short* o, int K, int N) {
        k_tcvt<<<(N * K + 255) / 256, 256, 0, stream>>>(in, o, K, N);
    };
    tc(mW1, mW1T, 256, HID);
    tc(mW2, mW2T, HID, D);
    tc(giW, giWT, D, 384);
    tc(giU, giUT, D, 384);
    tc(gtW, gtWT, D, 384);
    tc(gtU, gtUT, D, 384);
    tc(rW1, rW1T, D, HID);
    tc(rW2, rW2T, HID, 512);

    k_init_h<<<(N_TOTAL * D + 255) / 256, 256, 0, stream>>>(nodes, embed, h32, h16);
    k_build_int_edges<<<(NE_INT + 255) / 256, 256, 0, stream>>>(ie, srcA, dstA);
    k_build_tmp_edges<<<(NE_TMP + 255) / 256, 256, 0, stream>>>(srcT, dstT);
    hipMemsetAsync(cntA, 0, (size_t)N_TOTAL * 4, stream);
    hipMemsetAsync(cntT, 0, (size_t)N_TOTAL * 4, stream);
    k_count<<<(NE_INT + 255) / 256, 256, 0, stream>>>(dstA, NE_INT, cntA);
    k_count<<<(NE_TMP + 255) / 256, 256, 0, stream>>>(dstT, NE_TMP, cntT);

    int gmsgA = (NE_INT + 63) / 64;
    int gmsgT = (NE_TMP + 63) / 64;
    int ggru = (N_TOTAL + 63) / 64;
    for (int it = 0; it < 2; ++it) {
        hipMemsetAsync(agg, 0, (size_t)N_TOTAL * D * 4, stream);
        k_msg_mfma<<<gmsgA, 256, 0, stream>>>(h16, srcA, dstA, NE_INT, mW1T, mb1, mW2T, mb2, agg);
        k_gru_mfma<<<ggru, 256, 0, stream>>>(agg, cntA, h32, h16, giWT, giUT, gib);

        hipMemsetAsync(agg, 0, (size_t)N_TOTAL * D * 4, stream);
        k_msg_mfma<<<gmsgT, 256, 0, stream>>>(h16, srcT, dstT, NE_TMP, mW1T, mb1, mW2T, mb2, agg);
        k_gru_mfma<<<ggru, 256, 0, stream>>>(agg, cntT, h32, h16, gtWT, gtUT, gtb);
    }

    // readout
    dim3 g1(HID / 128, (N_NODES + 63) / 64);
    k_ro_mfma<<<g1, 256, 0, stream>>>(h16, rW1T, rb1, r1_32, r1_16, N_NODES, HID, D);
    dim3 g2(512 / 128, (N_NODES + 63) / 64);
    k_ro_mfma<<<g2, 256, 0, stream>>>(r1_16, rW2T, rb2, r2_32, r2_16, N_NODES, 512, HID);
    k_logits_softmax<<<N_NODES, 64, 0, stream>>>(r2_32, rW3, rb3, out);
}

// Round 3
// 1295.315 us; speedup vs baseline: 7.5631x; 1.4392x over previous
//
#include <hip/hip_runtime.h>
#include <math.h>

#define D 128
#define N_NODES 5000
#define WINDOW 10
#define N_TOTAL 50000
#define NE_INT 131072
#define NE_TMP 90000
#define NE_FWD (N_TOTAL - N_NODES)   // 45000
#define HID 1024

typedef short bf16x8 __attribute__((ext_vector_type(8)));
typedef float f32x4 __attribute__((ext_vector_type(4)));

#define SA 264   // Ain LDS row stride in shorts (256 + 8 pad)
#define SH 136   // 128 + 8 pad
#define SK 136   // 128 + 8 pad
#define SCAN_B 256

static __device__ __forceinline__ short f2bf(float f) {
    union { float f; unsigned u; } v; v.f = f;
    unsigned r = v.u + 0x7fffu + ((v.u >> 16) & 1u);   // RNE
    return (short)(r >> 16);
}
static __device__ __forceinline__ float bf2f(short s) {
    union { unsigned u; float f; } v;
    v.u = ((unsigned)(unsigned short)s) << 16;
    return v.f;
}

// ---------------- weight transpose + cvt: out[n*K+k] = bf16(in[k*N+n]) ----------------
__global__ void k_tcvt(const float* __restrict__ in, short* __restrict__ out, int K, int N) {
    int i = blockIdx.x * blockDim.x + threadIdx.x;
    if (i >= N * K) return;
    int n = i / K, k = i - n * K;
    out[i] = f2bf(in[(size_t)k * N + n]);
}

// ---------------- init h ----------------
__global__ void k_init_h(const int* __restrict__ nodes, const float* __restrict__ embed,
                         float* __restrict__ h32, short* __restrict__ h16) {
    int i = blockIdx.x * blockDim.x + threadIdx.x;
    if (i >= N_TOTAL * D) return;
    int row = i >> 7;
    int c = i & 127;
    int n = nodes[row / WINDOW];
    float v = embed[n * D + c];
    h32[i] = v;
    h16[i] = f2bf(v);
}

// ---------------- edge builders ----------------
__global__ void k_build_int_edges(const int* __restrict__ ie, int* __restrict__ src,
                                  int* __restrict__ dst, int* __restrict__ icnt) {
    int e = blockIdx.x * blockDim.x + threadIdx.x;
    if (e >= NE_INT) return;
    int t = ie[e * 3 + 0], a = ie[e * 3 + 1], b = ie[e * 3 + 2];
    int d = t * N_NODES + b;
    src[e] = t * N_NODES + a;
    dst[e] = d;
    atomicAdd(&icnt[d], 1);
}

__global__ void k_build_tmp_edges(int* __restrict__ src, int* __restrict__ dst) {
    int e = blockIdx.x * blockDim.x + threadIdx.x;
    if (e >= NE_TMP) return;
    int s, d;
    if (e < NE_FWD) { s = e; d = e + N_NODES; }
    else { int q = e - NE_FWD; s = q + N_NODES; d = q; }
    src[e] = s;
    dst[e] = d;
}

// ---------------- 3-kernel exclusive scan over icnt[N_TOTAL] -> rowstart ----------------
__global__ void k_scan_partial(const int* __restrict__ cnt, int* __restrict__ rowstart,
                               int* __restrict__ btot, int n) {
    __shared__ int s[SCAN_B];
    int tid = threadIdx.x;
    int i = blockIdx.x * SCAN_B + tid;
    int v = (i < n) ? cnt[i] : 0;
    s[tid] = v;
    __syncthreads();
    for (int off = 1; off < SCAN_B; off <<= 1) {
        int x = (tid >= off) ? s[tid - off] : 0;
        __syncthreads();
        s[tid] += x;
        __syncthreads();
    }
    if (i < n) rowstart[i] = s[tid] - v;   // block-local exclusive
    if (tid == SCAN_B - 1) btot[blockIdx.x] = s[tid];
}

__global__ void k_scan_block(int* __restrict__ btot, int nb) {
    __shared__ int s[SCAN_B];
    int tid = threadIdx.x;
    int v = (tid < nb) ? btot[tid] : 0;
    s[tid] = v;
    __syncthreads();
    for (int off = 1; off < SCAN_B; off <<= 1) {
        int x = (tid >= off) ? s[tid - off] : 0;
        __syncthreads();
        s[tid] += x;
        __syncthreads();
    }
    if (tid < nb) btot[tid] = s[tid] - v;  // exclusive block offsets
}

__global__ void k_scan_add(int* __restrict__ rowstart, const int* __restrict__ btot,
                           int* __restrict__ cursor, int n, int total) {
    int i = blockIdx.x * blockDim.x + threadIdx.x;
    if (i < n) {
        int v = rowstart[i] + btot[i >> 8];
        rowstart[i] = v;
        cursor[i] = v;
    }
    if (i == 0) rowstart[n] = total;
}

__global__ void k_fill_csr(const int* __restrict__ dst, int nE, int* __restrict__ cursor,
                           int* __restrict__ eidx) {
    int e = blockIdx.x * blockDim.x + threadIdx.x;
    if (e >= nE) return;
    int p = atomicAdd(&cursor[dst[e]], 1);
    eidx[p] = e;
}

// ---------------- fused message MLP (MFMA), dense bf16 m output ----------------
__global__ void __launch_bounds__(256, 2) k_msg_mfma(
    const short* __restrict__ h16, const int* __restrict__ src, const int* __restrict__ dst,
    int nE, const short* __restrict__ W1T, const float* __restrict__ b1,
    const short* __restrict__ W2T, const float* __restrict__ b2,
    short* __restrict__ m)
{
    __shared__ short Ain[64 * SA];   // [edge][0:256) = [h[src] | h[dst]] bf16
    __shared__ short Hid[64 * SH];   // [edge][128] hidden chunk bf16

    int t = threadIdx.x;
    int e0 = blockIdx.x * 64;

    // ---- gather: 4 threads/row, granule order g=i*4+q spreads LDS banks ----
    {
        int r = t >> 2, q = t & 3;
        int e = e0 + r;
        int ec = (e < nE) ? e : (nE - 1);
        int s = src[ec], d = dst[ec];
        const uint4* ps = (const uint4*)(h16 + (size_t)s * D);
        const uint4* pd = (const uint4*)(h16 + (size_t)d * D);
        uint4* ao = (uint4*)(Ain + r * SA);
#pragma unroll
        for (int i = 0; i < 8; ++i) {
            int g = i * 4 + q;
            ao[g] = (i < 4) ? ps[g] : pd[g - 16];
        }
    }
    __syncthreads();

    int w = t >> 6, lane = t & 63;
    int lm = lane & 15, lk = lane >> 4;

    // persistent GEMM2 accumulators: wave w owns out channels [32w, 32w+32)
    f32x4 c2[2][4];
#pragma unroll
    for (int cs = 0; cs < 2; ++cs) {
        int out0 = w * 32 + cs * 16 + lk * 4;
#pragma unroll
        for (int et = 0; et < 4; ++et)
#pragma unroll
            for (int rg = 0; rg < 4; ++rg) c2[cs][et][rg] = b2[out0 + rg];
    }

    for (int hc = 0; hc < 8; ++hc) {   // hidden chunks of 128
        f32x4 c1[2][4];
#pragma unroll
        for (int cs = 0; cs < 2; ++cs) {
            int ch0 = hc * 128 + (2 * w + cs) * 16 + lk * 4;
#pragma unroll
            for (int et = 0; et < 4; ++et)
#pragma unroll
                for (int rg = 0; rg < 4; ++rg) c1[cs][et][rg] = b1[ch0 + rg];
        }
#pragma unroll
        for (int kk = 0; kk < 8; ++kk) {
            int ko = kk * 32 + lk * 8;
            bf16x8 a0 = *(const bf16x8*)(W1T + (size_t)(hc * 128 + (2 * w) * 16 + lm) * 256 + ko);
            bf16x8 a1 = *(const bf16x8*)(W1T + (size_t)(hc * 128 + (2 * w + 1) * 16 + lm) * 256 + ko);
            bf16x8 bf[4];
#pragma unroll
            for (int et = 0; et < 4; ++et)
                bf[et] = *(const bf16x8*)(Ain + (et * 16 + lm) * SA + ko);
#pragma unroll
            for (int et = 0; et < 4; ++et) {
                c1[0][et] = __builtin_amdgcn_mfma_f32_16x16x32_bf16(a0, bf[et], c1[0][et], 0, 0, 0);
                c1[1][et] = __builtin_amdgcn_mfma_f32_16x16x32_bf16(a1, bf[et], c1[1][et], 0, 0, 0);
            }
        }
        __syncthreads();
#pragma unroll
        for (int cs = 0; cs < 2; ++cs) {
            int ch_in = (2 * w + cs) * 16 + lk * 4;
#pragma unroll
            for (int et = 0; et < 4; ++et) {
                int edge = et * 16 + lm;
                short4 sv;
                sv.x = f2bf(fmaxf(c1[cs][et][0], 0.f));
                sv.y = f2bf(fmaxf(c1[cs][et][1], 0.f));
                sv.z = f2bf(fmaxf(c1[cs][et][2], 0.f));
                sv.w = f2bf(fmaxf(c1[cs][et][3], 0.f));
                *(short4*)(Hid + edge * SH + ch_in) = sv;
            }
        }
        __syncthreads();
#pragma unroll
        for (int kk = 0; kk < 4; ++kk) {
            int ko = kk * 32 + lk * 8;
            bf16x8 a0 = *(const bf16x8*)(W2T + (size_t)(w * 32 + lm) * 1024 + hc * 128 + ko);
            bf16x8 a1 = *(const bf16x8*)(W2T + (size_t)(w * 32 + 16 + lm) * 1024 + hc * 128 + ko);
            bf16x8 bf[4];
#pragma unroll
            for (int et = 0; et < 4; ++et)
                bf[et] = *(const bf16x8*)(Hid + (et * 16 + lm) * SH + ko);
#pragma unroll
            for (int et = 0; et < 4; ++et) {
                c2[0][et] = __builtin_amdgcn_mfma_f32_16x16x32_bf16(a0, bf[et], c2[0][et], 0, 0, 0);
                c2[1][et] = __builtin_amdgcn_mfma_f32_16x16x32_bf16(a1, bf[et], c2[1][et], 0, 0, 0);
            }
        }
    }

    // ---- dense bf16 store: m[e][ch] = relu(msg) ----
#pragma unroll
    for (int et = 0; et < 4; ++et) {
        int edge = et * 16 + lm;
        int e = e0 + edge;
        if (e >= nE) continue;
        short* rowp = m + (size_t)e * 128;
#pragma unroll
        for (int cs = 0; cs < 2; ++cs) {
            int out0 = w * 32 + cs * 16 + lk * 4;
            short4 sv;
            sv.x = f2bf(fmaxf(c2[cs][et][0], 0.f));
            sv.y = f2bf(fmaxf(c2[cs][et][1], 0.f));
            sv.z = f2bf(fmaxf(c2[cs][et][2], 0.f));
            sv.w = f2bf(fmaxf(c2[cs][et][3], 0.f));
            *(short4*)(rowp + out0) = sv;
        }
    }
}

// ---------------- fused seg-mean (CSR or temporal) + GRU (MFMA), in place ----------------
// mode 0: CSR gather of m via rowstart/eidx. mode 1: temporal (affine dst).
__global__ void __launch_bounds__(256, 2) k_gru_mfma(
    const short* __restrict__ m, const int* __restrict__ rowstart,
    const int* __restrict__ eidx, int mode,
    float* __restrict__ h32, short* __restrict__ h16,
    const short* __restrict__ WT, const short* __restrict__ UT,
    const float* __restrict__ b)
{
    __shared__ short Ax[64 * SK];
    __shared__ short Hx[64 * SK];
    int t = threadIdx.x;
    int r0 = blockIdx.x * 64;

    {
        int r = t >> 2, q = t & 3;
        int row = r0 + r;
        int rc = (row < N_TOTAL) ? row : (N_TOTAL - 1);
        const uint4* hp = (const uint4*)(h16 + (size_t)rc * D);
        uint4* hxo = (uint4*)(Hx + r * SK);
#pragma unroll
        for (int i = 0; i < 4; ++i) hxo[q * 4 + i] = hp[q * 4 + i];

        float acc[32];
#pragma unroll
        for (int i = 0; i < 32; ++i) acc[i] = 0.f;
        int deg = 0;
        if (row < N_TOTAL) {
            if (mode == 0) {
                int s0 = rowstart[row], s1 = rowstart[row + 1];
                deg = s1 - s0;
                for (int p = s0; p < s1; ++p) {
                    int e = eidx[p];
                    const uint4* mp = (const uint4*)(m + (size_t)e * 128 + q * 32);
#pragma unroll
                    for (int i = 0; i < 4; ++i) {
                        uint4 v = mp[i];
                        const short* sp = (const short*)&v;
#pragma unroll
                        for (int j = 0; j < 8; ++j) acc[i * 8 + j] += bf2f(sp[j]);
                    }
                }
            } else {
                if (row >= N_NODES) {   // fwd edge e = row - N_NODES
                    const uint4* mp = (const uint4*)(m + (size_t)(row - N_NODES) * 128 + q * 32);
                    ++deg;
#pragma unroll
                    for (int i = 0; i < 4; ++i) {
                        uint4 v = mp[i];
                        const short* sp = (const short*)&v;
#pragma unroll
                        for (int j = 0; j < 8; ++j) acc[i * 8 + j] += bf2f(sp[j]);
                    }
                }
                if (row < NE_FWD) {     // bwd edge e = NE_FWD + row
                    const uint4* mp = (const uint4*)(m + (size_t)(NE_FWD + row) * 128 + q * 32);
                    ++deg;
#pragma unroll
                    for (int i = 0; i < 4; ++i) {
                        uint4 v = mp[i];
                        const short* sp = (const short*)&v;
#pragma unroll
                        for (int j = 0; j < 8; ++j) acc[i * 8 + j] += bf2f(sp[j]);
                    }
                }
            }
        }
        float inv = (deg > 0) ? 1.f / (float)deg : 0.f;
        uint4* axp = (uint4*)(Ax + r * SK + q * 32);
#pragma unroll
        for (int i = 0; i < 4; ++i) {
            union { uint4 u; short s[8]; } pk;
#pragma unroll
            for (int j = 0; j < 8; ++j) pk.s[j] = f2bf(acc[i * 8 + j] * inv);
            axp[i] = pk.u;
        }
    }
    __syncthreads();

    int w = t >> 6, lane = t & 63;
    int lm = lane & 15, lk = lane >> 4;

    for (int g = 0; g < 8; ++g) {
        int ch = g * 16 + lm;
        f32x4 cxz, cxr, cxh, chz, chr_, chh;
#pragma unroll
        for (int rg = 0; rg < 4; ++rg) {
            cxz[rg] = b[ch];        chz[rg] = b[384 + ch];
            cxr[rg] = b[128 + ch];  chr_[rg] = b[384 + 128 + ch];
            cxh[rg] = b[256 + ch];  chh[rg] = b[384 + 256 + ch];
        }
#pragma unroll
        for (int kk = 0; kk < 4; ++kk) {
            int ko = kk * 32 + lk * 8;
            bf16x8 ax = *(const bf16x8*)(Ax + (w * 16 + lm) * SK + ko);
            bf16x8 hx = *(const bf16x8*)(Hx + (w * 16 + lm) * SK + ko);
            bf16x8 bz = *(const bf16x8*)(WT + (size_t)(ch) * 128 + ko);
            bf16x8 br = *(const bf16x8*)(WT + (size_t)(128 + ch) * 128 + ko);
            bf16x8 bh = *(const bf16x8*)(WT + (size_t)(256 + ch) * 128 + ko);
            bf16x8 uz = *(const bf16x8*)(UT + (size_t)(ch) * 128 + ko);
            bf16x8 ur = *(const bf16x8*)(UT + (size_t)(128 + ch) * 128 + ko);
            bf16x8 uh = *(const bf16x8*)(UT + (size_t)(256 + ch) * 128 + ko);
            cxz = __builtin_amdgcn_mfma_f32_16x16x32_bf16(ax, bz, cxz, 0, 0, 0);
            cxr = __builtin_amdgcn_mfma_f32_16x16x32_bf16(ax, br, cxr, 0, 0, 0);
            cxh = __builtin_amdgcn_mfma_f32_16x16x32_bf16(ax, bh, cxh, 0, 0, 0);
            chz = __builtin_amdgcn_mfma_f32_16x16x32_bf16(hx, uz, chz, 0, 0, 0);
            chr_ = __builtin_amdgcn_mfma_f32_16x16x32_bf16(hx, ur, chr_, 0, 0, 0);
            chh = __builtin_amdgcn_mfma_f32_16x16x32_bf16(hx, uh, chh, 0, 0, 0);
        }
#pragma unroll
        for (int rg = 0; rg < 4; ++rg) {
            int row = r0 + w * 16 + lk * 4 + rg;
            if (row >= N_TOTAL) continue;
            float z = 1.f / (1.f + expf(-(cxz[rg] + chz[rg])));
            float r_ = 1.f / (1.f + expf(-(cxr[rg] + chr_[rg])));
            float hcv = tanhf(cxh[rg] + r_ * chh[rg]);
            size_t idx = (size_t)row * D + ch;
            float hold = h32[idx];
            float hnew = z * hold + (1.f - z) * hcv;
            h32[idx] = hnew;
            h16[idx] = f2bf(hnew);
        }
    }
}

// ---------------- generic MFMA GEMM: C = relu(A16 @ B + bias) ----------------
__global__ void __launch_bounds__(256, 2) k_ro_mfma(
    const short* __restrict__ A16, const short* __restrict__ BT,
    const float* __restrict__ bias, float* __restrict__ C32, short* __restrict__ C16,
    int M, int N, int K)
{
    __shared__ short As[64 * SK];
    int t = threadIdx.x;
    int mb = blockIdx.y * 64;
    int nb = blockIdx.x * 128;
    int w = t >> 6, lane = t & 63;
    int lm = lane & 15, lk = lane >> 4;

    f32x4 acc[8];
#pragma unroll
    for (int nt = 0; nt < 8; ++nt) {
        float bv = bias[nb + nt * 16 + lm];
        acc[nt][0] = bv; acc[nt][1] = bv; acc[nt][2] = bv; acc[nt][3] = bv;
    }

    for (int kc = 0; kc < K; kc += 128) {
        __syncthreads();
        {
            int r = t >> 2, q = t & 3;
            int row = mb + r;
            int rc = (row < M) ? row : (M - 1);
            const uint4* ap = (const uint4*)(A16 + (size_t)rc * K + kc);
            uint4* ao = (uint4*)(As + r * SK);
#pragma unroll
            for (int i = 0; i < 4; ++i) ao[i * 4 + q] = ap[i * 4 + q];
        }
        __syncthreads();
#pragma unroll
        for (int kk = 0; kk < 4; ++kk) {
            int ko = kk * 32 + lk * 8;
            bf16x8 a = *(const bf16x8*)(As + (w * 16 + lm) * SK + ko);
#pragma unroll
            for (int nt = 0; nt < 8; ++nt) {
                bf16x8 bfr = *(const bf16x8*)(BT + (size_t)(nb + nt * 16 + lm) * K + kc + ko);
                acc[nt] = __builtin_amdgcn_mfma_f32_16x16x32_bf16(a, bfr, acc[nt], 0, 0, 0);
            }
        }
    }
#pragma unroll
    for (int nt = 0; nt < 8; ++nt) {
        int col = nb + nt * 16 + lm;
#pragma unroll
        for (int rg = 0; rg < 4; ++rg) {
            int row = mb + w * 16 + lk * 4 + rg;
            if (row >= M) continue;
            float v = fmaxf(acc[nt][rg], 0.f);
            if (C32) C32[(size_t)row * N + col] = v;
            if (C16) C16[(size_t)row * N + col] = f2bf(v);
        }
    }
}

// ---------------- final 512x10 logits + softmax ----------------
__global__ void __launch_bounds__(64) k_logits_softmax(
    const float* __restrict__ r2, const float* __restrict__ W3,
    const float* __restrict__ b3, float* __restrict__ out)
{
    int row = blockIdx.x;
    int t = threadIdx.x;
    float p[10];
#pragma unroll
    for (int j = 0; j < 10; ++j) p[j] = 0.f;
    for (int k = t; k < 512; k += 64) {
        float v = r2[(size_t)row * 512 + k];
#pragma unroll
        for (int j = 0; j < 10; ++j) p[j] += v * W3[k * 10 + j];
    }
#pragma unroll
    for (int j = 0; j < 10; ++j) {
        float s = p[j];
        for (int off = 32; off > 0; off >>= 1) s += __shfl_down(s, off);
        p[j] = s;
    }
    if (t == 0) {
        float mx = -1e30f;
#pragma unroll
        for (int j = 0; j < 10; ++j) { p[j] += b3[j]; mx = fmaxf(mx, p[j]); }
        float sum = 0.f;
#pragma unroll
        for (int j = 0; j < 10; ++j) { p[j] = expf(p[j] - mx); sum += p[j]; }
        float inv = 1.f / sum;
#pragma unroll
        for (int j = 0; j < 10; ++j) out[(size_t)row * 10 + j] = p[j] * inv;
    }
}

extern "C" void kernel_launch(void* const* d_in, const int* in_sizes, int n_in,
                              void* d_out, int out_size, void* d_ws, size_t ws_size,
                              hipStream_t stream)
{
    const int*   ie    = (const int*)d_in[0];
    const int*   nodes = (const int*)d_in[1];
    const float* embed = (const float*)d_in[2];
    const float* mW1   = (const float*)d_in[3];
    const float* mb1   = (const float*)d_in[4];
    const float* mW2   = (const float*)d_in[5];
    const float* mb2   = (const float*)d_in[6];
    const float* giW   = (const float*)d_in[7];
    const float* giU   = (const float*)d_in[8];
    const float* gib   = (const float*)d_in[9];
    const float* gtW   = (const float*)d_in[10];
    const float* gtU   = (const float*)d_in[11];
    const float* gtb   = (const float*)d_in[12];
    const float* rW1   = (const float*)d_in[13];
    const float* rb1   = (const float*)d_in[14];
    const float* rW2   = (const float*)d_in[15];
    const float* rb2   = (const float*)d_in[16];
    const float* rW3   = (const float*)d_in[17];
    const float* rb3   = (const float*)d_in[18];
    float* out = (float*)d_out;

    char* ws = (char*)d_ws;
    size_t off = 0;
    auto alloc = [&](size_t bytes) {
        void* p = ws + off;
        off += (bytes + 255) & ~(size_t)255;
        return p;
    };
    float* h32   = (float*)alloc((size_t)N_TOTAL * D * 4);
    short* h16   = (short*)alloc((size_t)N_TOTAL * D * 2);
    short* m     = (short*)alloc((size_t)NE_INT * 128 * 2);   // edge messages, bf16
    int*   icnt  = (int*)alloc((size_t)N_TOTAL * 4);
    int*   rowst = (int*)alloc((size_t)(N_TOTAL + 1) * 4);
    int*   btot  = (int*)alloc(256 * 4);
    int*   curs  = (int*)alloc((size_t)N_TOTAL * 4);
    int*   eidx  = (int*)alloc((size_t)NE_INT * 4);
    int*   srcA  = (int*)alloc((size_t)NE_INT * 4);
    int*   dstA  = (int*)alloc((size_t)NE_INT * 4);
    int*   srcT  = (int*)alloc((size_t)NE_TMP * 4);
    int*   dstT  = (int*)alloc((size_t)NE_TMP * 4);
    short* mW1T  = (short*)alloc((size_t)HID * 256 * 2);
    short* mW2T  = (short*)alloc((size_t)D * HID * 2);
    short* giWT  = (short*)alloc((size_t)384 * D * 2);
    short* giUT  = (short*)alloc((size_t)384 * D * 2);
    short* gtWT  = (short*)alloc((size_t)384 * D * 2);
    short* gtUT  = (short*)alloc((size_t)384 * D * 2);
    short* rW1T  = (short*)alloc((size_t)HID * D * 2);
    short* rW2T  = (short*)alloc((size_t)512 * HID * 2);
    short* r1_16 = (short*)alloc((size_t)N_NODES * HID * 2);
    float* r2_32 = (float*)alloc((size_t)N_NODES * 512 * 4);

    // weight repack
    auto tc = [&](const float* in, short* o, int K, int N) {
        k_tcvt<<<(N * K + 255) / 256, 256, 0, stream>>>(in, o, K, N);
    };
    tc(mW1, mW1T, 256, HID);
    tc(mW2, mW2T, HID, D);
    tc(giW, giWT, D, 384);
    tc(giU, giUT, D, 384);
    tc(gtW, gtWT, D, 384);
    tc(gtU, gtUT, D, 384);
    tc(rW1, rW1T, D, HID);
    tc(rW2, rW2T, HID, 512);

    // init + CSR build (edges static across iterations)
    hipMemsetAsync(icnt, 0, (size_t)N_TOTAL * 4, stream);
    k_init_h<<<(N_TOTAL * D + 255) / 256, 256, 0, stream>>>(nodes, embed, h32, h16);
    k_build_int_edges<<<(NE_INT + 255) / 256, 256, 0, stream>>>(ie, srcA, dstA, icnt);
    k_build_tmp_edges<<<(NE_TMP + 255) / 256, 256, 0, stream>>>(srcT, dstT);
    int nb = (N_TOTAL + SCAN_B - 1) / SCAN_B;   // 196
    k_scan_partial<<<nb, SCAN_B, 0, stream>>>(icnt, rowst, btot, N_TOTAL);
    k_scan_block<<<1, SCAN_B, 0, stream>>>(btot, nb);
    k_scan_add<<<nb, SCAN_B, 0, stream>>>(rowst, btot, curs, N_TOTAL, NE_INT);
    k_fill_csr<<<(NE_INT + 255) / 256, 256, 0, stream>>>(dstA, NE_INT, curs, eidx);

    int gmsgA = (NE_INT + 63) / 64;
    int gmsgT = (NE_TMP + 63) / 64;
    int ggru = (N_TOTAL + 63) / 64;
    for (int it = 0; it < 2; ++it) {
        k_msg_mfma<<<gmsgA, 256, 0, stream>>>(h16, srcA, dstA, NE_INT, mW1T, mb1, mW2T, mb2, m);
        k_gru_mfma<<<ggru, 256, 0, stream>>>(m, rowst, eidx, 0, h32, h16, giWT, giUT, gib);

        k_msg_mfma<<<gmsgT, 256, 0, stream>>>(h16, srcT, dstT, NE_TMP, mW1T, mb1, mW2T, mb2, m);
        k_gru_mfma<<<ggru, 256, 0, stream>>>(m, rowst, eidx, 1, h32, h16, gtWT, gtUT, gtb);
    }

    // readout
    dim3 g1(HID / 128, (N_NODES + 63) / 64);
    k_ro_mfma<<<g1, 256, 0, stream>>>(h16, rW1T, rb1, (float*)nullptr, r1_16, N_NODES, HID, D);
    dim3 g2(512 / 128, (N_NODES + 63) / 64);
    k_ro_mfma<<<g2, 256, 0, stream>>>(r1_16, rW2T, rb2, r2_32, (short*)nullptr, N_NODES, 512, HID);
    k_logits_softmax<<<N_NODES, 64, 0, stream>>>(r2_32, rW3, rb3, out);
}